// Round 2
// baseline (18868.005 us; speedup 1.0000x reference)
//
#include <hip/hip_runtime.h>
#include <hip/hip_bf16.h>

#define T_SEQ 1024
#define BATCH 512
#define INPUT 64
#define HID   128

typedef __attribute__((ext_vector_type(8))) short bf16x8;
typedef __attribute__((ext_vector_type(4))) short s16x4;
typedef __attribute__((ext_vector_type(4))) float f32x4;

__device__ __forceinline__ short f2bf(float f) {
    union { float f; unsigned u; } v; v.f = f;
    unsigned r = (v.u + 0x7FFFu + ((v.u >> 16) & 1u)) >> 16;
    return (short)r;
}

// tanh(x) = 1 - 2/(exp(2x)+1); inf-safe (x->+inf: e=inf, rcp=0 -> 1; x->-inf: e=0 -> -1)
__device__ __forceinline__ float fast_tanh(float s) {
    float e = __expf(2.0f * s);
    return 1.0f - 2.0f * __builtin_amdgcn_rcpf(e + 1.0f);
}

__device__ __forceinline__ float hsig(float v) {
    return __builtin_amdgcn_fmed3f(v * 0.16666666666666666f + 0.5f, 0.0f, 1.0f);
}

// ---------------- prep: f32 -> bf16 bulk convert ----------------
__global__ __launch_bounds__(256) void cvt_kernel(const float* __restrict__ in,
                                                  short* __restrict__ out, int n4) {
    int i = blockIdx.x * 256 + threadIdx.x;
    if (i >= n4) return;
    f32x4 v = ((const f32x4*)in)[i];
    s16x4 o;
    for (int j = 0; j < 4; ++j) o[j] = f2bf(v[j]);
    ((s16x4*)out)[i] = o;
}

// ---------------- Stage 1: recurrence ----------------
// 32 blocks x 512 threads (8 waves). Block: 16 batches. Wave w: n-tile [16w,16w+16).
// 2 waves/SIMD for latency hiding. Gate GEMM pipelined one step late (off critical path).
template<bool PRE>
__global__ __launch_bounds__(512, 2) void rnn_kernel(
    const float* __restrict__ xf, const short* __restrict__ xb,
    const float* __restrict__ W_ih, const float* __restrict__ b_ih,
    const float* __restrict__ W_hh, const float* __restrict__ b_hh,
    const float* __restrict__ W_gate, const float* __restrict__ b_gate,
    float* __restrict__ agg_out)
{
    __shared__ short sh_h[2][16][136];   // pitch 136 = 17*8 shorts: b128-aligned reads

    const int tid  = threadIdx.x;
    const int wave = tid >> 6, lane = tid & 63;
    const int q = lane >> 4, l15 = lane & 15;
    const int b0 = blockIdx.x * 16;
    const int n0 = wave * 16;
    const int n  = n0 + l15;

    // one-time: weights -> bf16 B-frags in registers (lane holds B[q*8+j][l15])
    bf16x8 w1[6], wg[4];
    for (int kb = 0; kb < 6; ++kb) {
        const float* p = (kb < 2) ? (W_ih + n * INPUT + kb * 32 + q * 8)
                                  : (W_hh + n * HID + (kb - 2) * 32 + q * 8);
        bf16x8 f;
        for (int j = 0; j < 8; ++j) f[j] = f2bf(p[j]);
        w1[kb] = f;
    }
    for (int kb = 0; kb < 4; ++kb) {
        const float* p = W_gate + n * HID + kb * 32 + q * 8;
        bf16x8 f;
        for (int j = 0; j < 8; ++j) f[j] = f2bf(p[j]);
        wg[kb] = f;
    }
    const float b1 = b_ih[n] + b_hh[n], bgv = b_gate[n];
    f32x4 bias1v, biasgv, zero4;
    for (int r = 0; r < 4; ++r) { bias1v[r] = b1; biasgv[r] = bgv; zero4[r] = 0.0f; }

    f32x4 agg = zero4;
    float hn_prev[4] = {0.f, 0.f, 0.f, 0.f};
    bf16x8 hf[4];
    for (int kb = 0; kb < 4; ++kb)
        for (int j = 0; j < 8; ++j) hf[kb][j] = 0;

    // x A-frags: lane (q,l15) holds x[b0+l15][t][q*8+j] (frag0) and [32+q*8+j] (frag1)
    bf16x8 xa[2][2];
    const short* xq = nullptr;
    const float* xqf = nullptr;
    if (PRE) {
        const short* xp = xb + ((long)(b0 + l15) * T_SEQ) * INPUT + q * 8;
        xa[0][0] = *(const bf16x8*)(xp);
        xa[0][1] = *(const bf16x8*)(xp + 32);
        xa[1][0] = *(const bf16x8*)(xp + INPUT);
        xa[1][1] = *(const bf16x8*)(xp + INPUT + 32);
        xq = xp + 2 * INPUT;
    } else {
        const float* xp = xf + ((long)(b0 + l15) * T_SEQ) * INPUT + q * 8;
        for (int s = 0; s < 2; ++s) {
            f32x4 a0 = *(const f32x4*)(xp + s * INPUT);
            f32x4 a1 = *(const f32x4*)(xp + s * INPUT + 4);
            f32x4 a2 = *(const f32x4*)(xp + s * INPUT + 32);
            f32x4 a3 = *(const f32x4*)(xp + s * INPUT + 36);
            for (int j = 0; j < 4; ++j) {
                xa[s][0][j] = f2bf(a0[j]); xa[s][0][4 + j] = f2bf(a1[j]);
                xa[s][1][j] = f2bf(a2[j]); xa[s][1][4 + j] = f2bf(a3[j]);
            }
        }
        xqf = xp + 2 * INPUT;
    }

    // pre-accumulate x-part for t=0
    f32x4 accx;
    accx = __builtin_amdgcn_mfma_f32_16x16x32_bf16(xa[0][0], w1[0], bias1v, 0, 0, 0);
    accx = __builtin_amdgcn_mfma_f32_16x16x32_bf16(xa[0][1], w1[1], accx, 0, 0, 0);

    for (int t = 0; t < T_SEQ; ++t) {
        const int slot = t & 1, ns = slot ^ 1;

        // prefetch x_{t+2} into xa[slot] (old contents consumed last iter)
        if (PRE) {
            xa[slot][0] = *(const bf16x8*)(xq);
            xa[slot][1] = *(const bf16x8*)(xq + 32);
            if (t < T_SEQ - 3) xq += INPUT;
        } else {
            f32x4 a0 = *(const f32x4*)(xqf);
            f32x4 a1 = *(const f32x4*)(xqf + 4);
            f32x4 a2 = *(const f32x4*)(xqf + 32);
            f32x4 a3 = *(const f32x4*)(xqf + 36);
            for (int j = 0; j < 4; ++j) {
                xa[slot][0][j] = f2bf(a0[j]); xa[slot][0][4 + j] = f2bf(a1[j]);
                xa[slot][1][j] = f2bf(a2[j]); xa[slot][1][4 + j] = f2bf(a3[j]);
            }
            if (t < T_SEQ - 3) xqf += INPUT;
        }

        // h(t) h-part: 2 independent 2-deep chains onto precomputed accx.
        // gate(h(t-1)): 2 independent 2-deep chains (same hf operands, off critical path).
        f32x4 accA = __builtin_amdgcn_mfma_f32_16x16x32_bf16(hf[0], w1[2], accx, 0, 0, 0);
        f32x4 accB = __builtin_amdgcn_mfma_f32_16x16x32_bf16(hf[2], w1[4], zero4, 0, 0, 0);
        f32x4 gA   = __builtin_amdgcn_mfma_f32_16x16x32_bf16(hf[0], wg[0], biasgv, 0, 0, 0);
        f32x4 gB   = __builtin_amdgcn_mfma_f32_16x16x32_bf16(hf[2], wg[2], zero4, 0, 0, 0);
        accA = __builtin_amdgcn_mfma_f32_16x16x32_bf16(hf[1], w1[3], accA, 0, 0, 0);
        accB = __builtin_amdgcn_mfma_f32_16x16x32_bf16(hf[3], w1[5], accB, 0, 0, 0);
        gA   = __builtin_amdgcn_mfma_f32_16x16x32_bf16(hf[1], wg[1], gA, 0, 0, 0);
        gB   = __builtin_amdgcn_mfma_f32_16x16x32_bf16(hf[3], wg[3], gB, 0, 0, 0);
        // x-part for t+1 (independent)
        accx = __builtin_amdgcn_mfma_f32_16x16x32_bf16(xa[ns][0], w1[0], bias1v, 0, 0, 0);
        accx = __builtin_amdgcn_mfma_f32_16x16x32_bf16(xa[ns][1], w1[1], accx, 0, 0, 0);

        float hn[4];
        for (int r = 0; r < 4; ++r) hn[r] = fast_tanh(accA[r] + accB[r]);
        for (int r = 0; r < 4; ++r) agg[r] += hn_prev[r] * hsig(gA[r] + gB[r]);

        for (int r = 0; r < 4; ++r)
            sh_h[slot][q * 4 + r][n0 + l15] = f2bf(hn[r]);
        __syncthreads();
        for (int kb = 0; kb < 4; ++kb)
            hf[kb] = *(const bf16x8*)&sh_h[slot][l15][kb * 32 + q * 8];
        for (int r = 0; r < 4; ++r) hn_prev[r] = hn[r];
    }

    // epilogue: gate for h(T-1)
    f32x4 gA = __builtin_amdgcn_mfma_f32_16x16x32_bf16(hf[0], wg[0], biasgv, 0, 0, 0);
    f32x4 gB = __builtin_amdgcn_mfma_f32_16x16x32_bf16(hf[2], wg[2], zero4, 0, 0, 0);
    gA = __builtin_amdgcn_mfma_f32_16x16x32_bf16(hf[1], wg[1], gA, 0, 0, 0);
    gB = __builtin_amdgcn_mfma_f32_16x16x32_bf16(hf[3], wg[3], gB, 0, 0, 0);

    const float s = 1.0f / (float)T_SEQ;
    for (int r = 0; r < 4; ++r) {
        float a = agg[r] + hn_prev[r] * hsig(gA[r] + gB[r]);
        agg_out[(b0 + q * 4 + r) * HID + n] = a * s;
    }
}

// ---------------- Stage 2a: mapped = agg @ W_map^T + b_map ----------------
template<bool PRE>
__global__ __launch_bounds__(256) void map_kernel(
    const float* __restrict__ agg, const float* __restrict__ Wf,
    const short* __restrict__ Wb, const float* __restrict__ b_map,
    float* __restrict__ mapped)
{
    const int tid  = threadIdx.x;
    const int wave = tid >> 6, lane = tid & 63;
    const int q = lane >> 4, l15 = lane & 15;
    const int mb = blockIdx.x & 31;
    const int nb = blockIdx.x >> 5;
    const int b0 = mb * 16;
    const int n0 = nb * 128 + wave * 32;

    bf16x8 af[4];
    for (int kb = 0; kb < 4; ++kb) {
        const float* p = agg + (b0 + l15) * HID + kb * 32 + q * 8;
        bf16x8 f;
        for (int j = 0; j < 8; ++j) f[j] = f2bf(p[j]);
        af[kb] = f;
    }
    for (int tn = 0; tn < 2; ++tn) {
        int nn = n0 + tn * 16 + l15;
        float bias = b_map[nn];
        f32x4 c;
        for (int r = 0; r < 4; ++r) c[r] = bias;
        for (int kb = 0; kb < 4; ++kb) {
            bf16x8 f;
            if (PRE) {
                f = *(const bf16x8*)(Wb + (long)nn * HID + kb * 32 + q * 8);
            } else {
                const float* p = Wf + (long)nn * HID + kb * 32 + q * 8;
                for (int j = 0; j < 8; ++j) f[j] = f2bf(p[j]);
            }
            c = __builtin_amdgcn_mfma_f32_16x16x32_bf16(af[kb], f, c, 0, 0, 0);
        }
        for (int r = 0; r < 4; ++r)
            mapped[(long)(b0 + q * 4 + r) * 16384 + nn] = c[r];
    }
}

// ---------------- Stage 2b: pool 4x4 -> hardsigmoid -> gate (in place) ----------------
__global__ __launch_bounds__(256) void pool_gate_kernel(float* __restrict__ mapped)
{
    __shared__ float sh_part[256];
    __shared__ float sh_gate[64];
    const int tid = threadIdx.x;
    float* plane = mapped + (long)blockIdx.x * 1024;

    f32x4 m4 = *(const f32x4*)(plane + tid * 4);
    sh_part[tid] = m4[0] + m4[1] + m4[2] + m4[3];
    __syncthreads();
    if (tid < 64) {
        int ph = tid >> 3, pw = tid & 7;
        float s = 0.0f;
        for (int i = 0; i < 4; ++i) s += sh_part[(4 * ph + i) * 8 + pw];
        sh_gate[tid] = hsig(s * (1.0f / 16.0f));
    }
    __syncthreads();
    int h = tid >> 3, wb = tid & 7;
    float g = sh_gate[(h >> 2) * 8 + wb];
    f32x4 o = m4 * g;
    *(f32x4*)(plane + tid * 4) = o;
}

extern "C" void kernel_launch(void* const* d_in, const int* in_sizes, int n_in,
                              void* d_out, int out_size, void* d_ws, size_t ws_size,
                              hipStream_t stream) {
    const float* x      = (const float*)d_in[0];
    const float* W_ih   = (const float*)d_in[1];
    const float* b_ih   = (const float*)d_in[2];
    const float* W_hh   = (const float*)d_in[3];
    const float* b_hh   = (const float*)d_in[4];
    const float* W_gate = (const float*)d_in[5];
    const float* b_gate = (const float*)d_in[6];
    const float* W_map  = (const float*)d_in[7];
    const float* b_map  = (const float*)d_in[8];
    float* out = (float*)d_out;

    const size_t xb_bytes = (size_t)BATCH * T_SEQ * INPUT * 2;     // 67,108,864
    const size_t wm_bytes = (size_t)16384 * HID * 2;               //  4,194,304
    const size_t agg_bytes = (size_t)BATCH * HID * 4;              //    262,144
    const bool pre = ws_size >= xb_bytes + wm_bytes + agg_bytes;

    if (pre) {
        short* x_bf  = (short*)d_ws;
        short* wm_bf = (short*)((char*)d_ws + xb_bytes);
        float* agg   = (float*)((char*)d_ws + xb_bytes + wm_bytes);

        cvt_kernel<<<(BATCH * T_SEQ * INPUT / 4 + 255) / 256, 256, 0, stream>>>(x, x_bf, BATCH * T_SEQ * INPUT / 4);
        cvt_kernel<<<(16384 * HID / 4 + 255) / 256, 256, 0, stream>>>(W_map, wm_bf, 16384 * HID / 4);
        rnn_kernel<true><<<32, 512, 0, stream>>>(x, x_bf, W_ih, b_ih, W_hh, b_hh,
                                                 W_gate, b_gate, agg);
        map_kernel<true><<<4096, 256, 0, stream>>>(agg, W_map, wm_bf, b_map, out);
    } else {
        float* agg = (float*)d_ws;
        rnn_kernel<false><<<32, 512, 0, stream>>>(x, nullptr, W_ih, b_ih, W_hh, b_hh,
                                                  W_gate, b_gate, agg);
        map_kernel<false><<<4096, 256, 0, stream>>>(agg, W_map, nullptr, b_map, out);
    }
    pool_gate_kernel<<<BATCH * 16, 256, 0, stream>>>(out);
}

// Round 3
// 714.812 us; speedup vs baseline: 26.3958x; 26.3958x over previous
//
#include <hip/hip_runtime.h>
#include <hip/hip_bf16.h>

#define T_SEQ 1024
#define BATCH 512
#define INPUT 64
#define HID   128

typedef __attribute__((ext_vector_type(8))) short bf16x8;
typedef __attribute__((ext_vector_type(4))) short s16x4;
typedef __attribute__((ext_vector_type(4))) float f32x4;

__device__ __forceinline__ short f2bf(float f) {
    union { float f; unsigned u; } v; v.f = f;
    unsigned r = (v.u + 0x7FFFu + ((v.u >> 16) & 1u)) >> 16;
    return (short)r;
}

// tanh(x) = 1 - 2/(exp(2x)+1); inf-safe
__device__ __forceinline__ float fast_tanh(float s) {
    float e = __expf(2.0f * s);
    return 1.0f - 2.0f * __builtin_amdgcn_rcpf(e + 1.0f);
}

__device__ __forceinline__ float hsig(float v) {
    return __builtin_amdgcn_fmed3f(v * 0.16666666666666666f + 0.5f, 0.0f, 1.0f);
}

// ---------------- prep: f32 -> bf16 bulk convert ----------------
__global__ __launch_bounds__(256) void cvt_kernel(const float* __restrict__ in,
                                                  short* __restrict__ out, int n4) {
    int i = blockIdx.x * 256 + threadIdx.x;
    if (i >= n4) return;
    f32x4 v = ((const f32x4*)in)[i];
    s16x4 o;
    #pragma unroll
    for (int j = 0; j < 4; ++j) o[j] = f2bf(v[j]);
    ((s16x4*)out)[i] = o;
}

// ---------------- Stage 1: recurrence ----------------
// 32 blocks x 512 threads (8 waves, 2/SIMD). Block: 16 batches. Wave w: cols [16w,16w+16).
// Manual 2x unroll: NO runtime-indexed private arrays (R2's scratch-spill bug).
template<bool PRE>
__global__ __launch_bounds__(512, 2) void rnn_kernel(
    const float* __restrict__ xf, const short* __restrict__ xb,
    const float* __restrict__ W_ih, const float* __restrict__ b_ih,
    const float* __restrict__ W_hh, const float* __restrict__ b_hh,
    const float* __restrict__ W_gate, const float* __restrict__ b_gate,
    float* __restrict__ agg_out)
{
    __shared__ short sh0[16][136];   // pitch 136 shorts = 17*16B: aligned b128 reads
    __shared__ short sh1[16][136];

    const int tid  = threadIdx.x;
    const int wave = tid >> 6, lane = tid & 63;
    const int q = lane >> 4, l15 = lane & 15;
    const int b0 = blockIdx.x * 16;
    const int n0 = wave * 16;
    const int n  = n0 + l15;

    // one-time: weights -> bf16 B-frags in registers (lane holds B[q*8+j][l15])
    bf16x8 w1[6], wg[4];
    #pragma unroll
    for (int kb = 0; kb < 6; ++kb) {
        const float* p = (kb < 2) ? (W_ih + n * INPUT + kb * 32 + q * 8)
                                  : (W_hh + n * HID + (kb - 2) * 32 + q * 8);
        bf16x8 f;
        #pragma unroll
        for (int j = 0; j < 8; ++j) f[j] = f2bf(p[j]);
        w1[kb] = f;
    }
    #pragma unroll
    for (int kb = 0; kb < 4; ++kb) {
        const float* p = W_gate + n * HID + kb * 32 + q * 8;
        bf16x8 f;
        #pragma unroll
        for (int j = 0; j < 8; ++j) f[j] = f2bf(p[j]);
        wg[kb] = f;
    }
    const float b1 = b_ih[n] + b_hh[n], bgv = b_gate[n];
    f32x4 bias1v, biasgv, zero4;
    #pragma unroll
    for (int r = 0; r < 4; ++r) { bias1v[r] = b1; biasgv[r] = bgv; zero4[r] = 0.0f; }

    f32x4 agg = zero4;
    float hp0 = 0.f, hp1 = 0.f, hp2 = 0.f, hp3 = 0.f;   // h(t-1), this lane's 4 rows
    bf16x8 hf0, hf1, hf2, hf3;                          // A-frags of h(t-1)
    #pragma unroll
    for (int j = 0; j < 8; ++j) { hf0[j] = 0; hf1[j] = 0; hf2[j] = 0; hf3[j] = 0; }

    // x A-frags, explicit double buffer (even buffer xaE*, odd buffer xaO*)
    bf16x8 xaE0, xaE1, xaO0, xaO1;
    const short* xq = nullptr;
    const float* xqf = nullptr;
    if (PRE) {
        const short* xp = xb + ((long)(b0 + l15) * T_SEQ) * INPUT + q * 8;
        xaE0 = *(const bf16x8*)(xp);
        xaE1 = *(const bf16x8*)(xp + 32);
        xaO0 = *(const bf16x8*)(xp + INPUT);
        xaO1 = *(const bf16x8*)(xp + INPUT + 32);
        xq = xp + 2 * INPUT;
    } else {
        const float* xp = xf + ((long)(b0 + l15) * T_SEQ) * INPUT + q * 8;
        f32x4 a0 = *(const f32x4*)(xp),          a1 = *(const f32x4*)(xp + 4);
        f32x4 a2 = *(const f32x4*)(xp + 32),     a3 = *(const f32x4*)(xp + 36);
        f32x4 c0 = *(const f32x4*)(xp + 64),     c1 = *(const f32x4*)(xp + 68);
        f32x4 c2 = *(const f32x4*)(xp + 96),     c3 = *(const f32x4*)(xp + 100);
        #pragma unroll
        for (int j = 0; j < 4; ++j) {
            xaE0[j] = f2bf(a0[j]); xaE0[4 + j] = f2bf(a1[j]);
            xaE1[j] = f2bf(a2[j]); xaE1[4 + j] = f2bf(a3[j]);
            xaO0[j] = f2bf(c0[j]); xaO0[4 + j] = f2bf(c1[j]);
            xaO1[j] = f2bf(c2[j]); xaO1[4 + j] = f2bf(c3[j]);
        }
        xqf = xp + 2 * INPUT;
    }

    // x-part for t=0 (even buffer)
    f32x4 accx;
    accx = __builtin_amdgcn_mfma_f32_16x16x32_bf16(xaE0, w1[0], bias1v, 0, 0, 0);
    accx = __builtin_amdgcn_mfma_f32_16x16x32_bf16(xaE1, w1[1], accx, 0, 0, 0);

    for (int i = 0; i < T_SEQ / 2; ++i) {
        // ================= even step: t = 2i =================
        {
            const int t = 2 * i;
            // prefetch x(t+2) -> even buffer (its old value was consumed at t-1)
            if (PRE) {
                xaE0 = *(const bf16x8*)(xq);
                xaE1 = *(const bf16x8*)(xq + 32);
                if (t < T_SEQ - 3) xq += INPUT;
            } else {
                f32x4 a0 = *(const f32x4*)(xqf),      a1 = *(const f32x4*)(xqf + 4);
                f32x4 a2 = *(const f32x4*)(xqf + 32), a3 = *(const f32x4*)(xqf + 36);
                #pragma unroll
                for (int j = 0; j < 4; ++j) {
                    xaE0[j] = f2bf(a0[j]); xaE0[4 + j] = f2bf(a1[j]);
                    xaE1[j] = f2bf(a2[j]); xaE1[4 + j] = f2bf(a3[j]);
                }
                if (t < T_SEQ - 3) xqf += INPUT;
            }

            f32x4 accA = __builtin_amdgcn_mfma_f32_16x16x32_bf16(hf0, w1[2], accx, 0, 0, 0);
            f32x4 accB = __builtin_amdgcn_mfma_f32_16x16x32_bf16(hf2, w1[4], zero4, 0, 0, 0);
            f32x4 gA   = __builtin_amdgcn_mfma_f32_16x16x32_bf16(hf0, wg[0], biasgv, 0, 0, 0);
            f32x4 gB   = __builtin_amdgcn_mfma_f32_16x16x32_bf16(hf2, wg[2], zero4, 0, 0, 0);
            accA = __builtin_amdgcn_mfma_f32_16x16x32_bf16(hf1, w1[3], accA, 0, 0, 0);
            accB = __builtin_amdgcn_mfma_f32_16x16x32_bf16(hf3, w1[5], accB, 0, 0, 0);
            gA   = __builtin_amdgcn_mfma_f32_16x16x32_bf16(hf1, wg[1], gA, 0, 0, 0);
            gB   = __builtin_amdgcn_mfma_f32_16x16x32_bf16(hf3, wg[3], gB, 0, 0, 0);
            // x-part for t+1 (odd buffer)
            accx = __builtin_amdgcn_mfma_f32_16x16x32_bf16(xaO0, w1[0], bias1v, 0, 0, 0);
            accx = __builtin_amdgcn_mfma_f32_16x16x32_bf16(xaO1, w1[1], accx, 0, 0, 0);

            float h0 = fast_tanh(accA[0] + accB[0]);
            float h1 = fast_tanh(accA[1] + accB[1]);
            float h2 = fast_tanh(accA[2] + accB[2]);
            float h3 = fast_tanh(accA[3] + accB[3]);
            agg[0] += hp0 * hsig(gA[0] + gB[0]);
            agg[1] += hp1 * hsig(gA[1] + gB[1]);
            agg[2] += hp2 * hsig(gA[2] + gB[2]);
            agg[3] += hp3 * hsig(gA[3] + gB[3]);

            sh0[q * 4 + 0][n] = f2bf(h0);
            sh0[q * 4 + 1][n] = f2bf(h1);
            sh0[q * 4 + 2][n] = f2bf(h2);
            sh0[q * 4 + 3][n] = f2bf(h3);
            __syncthreads();
            hf0 = *(const bf16x8*)&sh0[l15][q * 8];
            hf1 = *(const bf16x8*)&sh0[l15][32 + q * 8];
            hf2 = *(const bf16x8*)&sh0[l15][64 + q * 8];
            hf3 = *(const bf16x8*)&sh0[l15][96 + q * 8];
            hp0 = h0; hp1 = h1; hp2 = h2; hp3 = h3;
        }
        // ================= odd step: t = 2i+1 =================
        {
            const int t = 2 * i + 1;
            // prefetch x(t+2) -> odd buffer
            if (PRE) {
                xaO0 = *(const bf16x8*)(xq);
                xaO1 = *(const bf16x8*)(xq + 32);
                if (t < T_SEQ - 3) xq += INPUT;
            } else {
                f32x4 a0 = *(const f32x4*)(xqf),      a1 = *(const f32x4*)(xqf + 4);
                f32x4 a2 = *(const f32x4*)(xqf + 32), a3 = *(const f32x4*)(xqf + 36);
                #pragma unroll
                for (int j = 0; j < 4; ++j) {
                    xaO0[j] = f2bf(a0[j]); xaO0[4 + j] = f2bf(a1[j]);
                    xaO1[j] = f2bf(a2[j]); xaO1[4 + j] = f2bf(a3[j]);
                }
                if (t < T_SEQ - 3) xqf += INPUT;
            }

            f32x4 accA = __builtin_amdgcn_mfma_f32_16x16x32_bf16(hf0, w1[2], accx, 0, 0, 0);
            f32x4 accB = __builtin_amdgcn_mfma_f32_16x16x32_bf16(hf2, w1[4], zero4, 0, 0, 0);
            f32x4 gA   = __builtin_amdgcn_mfma_f32_16x16x32_bf16(hf0, wg[0], biasgv, 0, 0, 0);
            f32x4 gB   = __builtin_amdgcn_mfma_f32_16x16x32_bf16(hf2, wg[2], zero4, 0, 0, 0);
            accA = __builtin_amdgcn_mfma_f32_16x16x32_bf16(hf1, w1[3], accA, 0, 0, 0);
            accB = __builtin_amdgcn_mfma_f32_16x16x32_bf16(hf3, w1[5], accB, 0, 0, 0);
            gA   = __builtin_amdgcn_mfma_f32_16x16x32_bf16(hf1, wg[1], gA, 0, 0, 0);
            gB   = __builtin_amdgcn_mfma_f32_16x16x32_bf16(hf3, wg[3], gB, 0, 0, 0);
            // x-part for t+1 (even buffer, freshly prefetched last even step)
            accx = __builtin_amdgcn_mfma_f32_16x16x32_bf16(xaE0, w1[0], bias1v, 0, 0, 0);
            accx = __builtin_amdgcn_mfma_f32_16x16x32_bf16(xaE1, w1[1], accx, 0, 0, 0);

            float h0 = fast_tanh(accA[0] + accB[0]);
            float h1 = fast_tanh(accA[1] + accB[1]);
            float h2 = fast_tanh(accA[2] + accB[2]);
            float h3 = fast_tanh(accA[3] + accB[3]);
            agg[0] += hp0 * hsig(gA[0] + gB[0]);
            agg[1] += hp1 * hsig(gA[1] + gB[1]);
            agg[2] += hp2 * hsig(gA[2] + gB[2]);
            agg[3] += hp3 * hsig(gA[3] + gB[3]);

            sh1[q * 4 + 0][n] = f2bf(h0);
            sh1[q * 4 + 1][n] = f2bf(h1);
            sh1[q * 4 + 2][n] = f2bf(h2);
            sh1[q * 4 + 3][n] = f2bf(h3);
            __syncthreads();
            hf0 = *(const bf16x8*)&sh1[l15][q * 8];
            hf1 = *(const bf16x8*)&sh1[l15][32 + q * 8];
            hf2 = *(const bf16x8*)&sh1[l15][64 + q * 8];
            hf3 = *(const bf16x8*)&sh1[l15][96 + q * 8];
            hp0 = h0; hp1 = h1; hp2 = h2; hp3 = h3;
        }
    }

    // epilogue: gate for h(T-1)
    f32x4 gA = __builtin_amdgcn_mfma_f32_16x16x32_bf16(hf0, wg[0], biasgv, 0, 0, 0);
    f32x4 gB = __builtin_amdgcn_mfma_f32_16x16x32_bf16(hf2, wg[2], zero4, 0, 0, 0);
    gA = __builtin_amdgcn_mfma_f32_16x16x32_bf16(hf1, wg[1], gA, 0, 0, 0);
    gB = __builtin_amdgcn_mfma_f32_16x16x32_bf16(hf3, wg[3], gB, 0, 0, 0);

    const float s = 1.0f / (float)T_SEQ;
    agg_out[(b0 + q * 4 + 0) * HID + n] = (agg[0] + hp0 * hsig(gA[0] + gB[0])) * s;
    agg_out[(b0 + q * 4 + 1) * HID + n] = (agg[1] + hp1 * hsig(gA[1] + gB[1])) * s;
    agg_out[(b0 + q * 4 + 2) * HID + n] = (agg[2] + hp2 * hsig(gA[2] + gB[2])) * s;
    agg_out[(b0 + q * 4 + 3) * HID + n] = (agg[3] + hp3 * hsig(gA[3] + gB[3])) * s;
}

// ---------------- Stage 2a: mapped = agg @ W_map^T + b_map ----------------
template<bool PRE>
__global__ __launch_bounds__(256) void map_kernel(
    const float* __restrict__ agg, const float* __restrict__ Wf,
    const short* __restrict__ Wb, const float* __restrict__ b_map,
    float* __restrict__ mapped)
{
    const int tid  = threadIdx.x;
    const int wave = tid >> 6, lane = tid & 63;
    const int q = lane >> 4, l15 = lane & 15;
    const int mb = blockIdx.x & 31;
    const int nb = blockIdx.x >> 5;
    const int b0 = mb * 16;
    const int n0 = nb * 128 + wave * 32;

    bf16x8 af[4];
    #pragma unroll
    for (int kb = 0; kb < 4; ++kb) {
        const float* p = agg + (b0 + l15) * HID + kb * 32 + q * 8;
        bf16x8 f;
        #pragma unroll
        for (int j = 0; j < 8; ++j) f[j] = f2bf(p[j]);
        af[kb] = f;
    }
    #pragma unroll
    for (int tn = 0; tn < 2; ++tn) {
        int nn = n0 + tn * 16 + l15;
        float bias = b_map[nn];
        f32x4 c;
        #pragma unroll
        for (int r = 0; r < 4; ++r) c[r] = bias;
        #pragma unroll
        for (int kb = 0; kb < 4; ++kb) {
            bf16x8 f;
            if (PRE) {
                f = *(const bf16x8*)(Wb + (long)nn * HID + kb * 32 + q * 8);
            } else {
                const float* p = Wf + (long)nn * HID + kb * 32 + q * 8;
                #pragma unroll
                for (int j = 0; j < 8; ++j) f[j] = f2bf(p[j]);
            }
            c = __builtin_amdgcn_mfma_f32_16x16x32_bf16(af[kb], f, c, 0, 0, 0);
        }
        #pragma unroll
        for (int r = 0; r < 4; ++r)
            mapped[(long)(b0 + q * 4 + r) * 16384 + nn] = c[r];
    }
}

// ---------------- Stage 2b: pool 4x4 -> hardsigmoid -> gate (in place) ----------------
__global__ __launch_bounds__(256) void pool_gate_kernel(float* __restrict__ mapped)
{
    __shared__ float sh_part[256];
    __shared__ float sh_gate[64];
    const int tid = threadIdx.x;
    float* plane = mapped + (long)blockIdx.x * 1024;

    f32x4 m4 = *(const f32x4*)(plane + tid * 4);
    sh_part[tid] = m4[0] + m4[1] + m4[2] + m4[3];
    __syncthreads();
    if (tid < 64) {
        int ph = tid >> 3, pw = tid & 7;
        float s = 0.0f;
        #pragma unroll
        for (int i = 0; i < 4; ++i) s += sh_part[(4 * ph + i) * 8 + pw];
        sh_gate[tid] = hsig(s * (1.0f / 16.0f));
    }
    __syncthreads();
    int h = tid >> 3, wb = tid & 7;
    float g = sh_gate[(h >> 2) * 8 + wb];
    f32x4 o = m4 * g;
    *(f32x4*)(plane + tid * 4) = o;
}

extern "C" void kernel_launch(void* const* d_in, const int* in_sizes, int n_in,
                              void* d_out, int out_size, void* d_ws, size_t ws_size,
                              hipStream_t stream) {
    const float* x      = (const float*)d_in[0];
    const float* W_ih   = (const float*)d_in[1];
    const float* b_ih   = (const float*)d_in[2];
    const float* W_hh   = (const float*)d_in[3];
    const float* b_hh   = (const float*)d_in[4];
    const float* W_gate = (const float*)d_in[5];
    const float* b_gate = (const float*)d_in[6];
    const float* W_map  = (const float*)d_in[7];
    const float* b_map  = (const float*)d_in[8];
    float* out = (float*)d_out;

    const size_t xb_bytes = (size_t)BATCH * T_SEQ * INPUT * 2;
    const size_t wm_bytes = (size_t)16384 * HID * 2;
    const size_t agg_bytes = (size_t)BATCH * HID * 4;
    const bool pre = ws_size >= xb_bytes + wm_bytes + agg_bytes;

    if (pre) {
        short* x_bf  = (short*)d_ws;
        short* wm_bf = (short*)((char*)d_ws + xb_bytes);
        float* agg   = (float*)((char*)d_ws + xb_bytes + wm_bytes);

        cvt_kernel<<<(BATCH * T_SEQ * INPUT / 4 + 255) / 256, 256, 0, stream>>>(x, x_bf, BATCH * T_SEQ * INPUT / 4);
        cvt_kernel<<<(16384 * HID / 4 + 255) / 256, 256, 0, stream>>>(W_map, wm_bf, 16384 * HID / 4);
        rnn_kernel<true><<<32, 512, 0, stream>>>(x, x_bf, W_ih, b_ih, W_hh, b_hh,
                                                 W_gate, b_gate, agg);
        map_kernel<true><<<4096, 256, 0, stream>>>(agg, W_map, wm_bf, b_map, out);
    } else {
        float* agg = (float*)d_ws;
        rnn_kernel<false><<<32, 512, 0, stream>>>(x, nullptr, W_ih, b_ih, W_hh, b_hh,
                                                  W_gate, b_gate, agg);
        map_kernel<false><<<4096, 256, 0, stream>>>(agg, W_map, nullptr, b_map, out);
    }
    pool_gate_kernel<<<BATCH * 16, 256, 0, stream>>>(out);
}